// Round 2
// baseline (2846.125 us; speedup 1.0000x reference)
//
#include <hip/hip_runtime.h>
#include <math.h>

#define TT 2048
#define UU 64
#define BB 256
#define NTHR 128        // 2 waves: wave0 = layer-0 producer, wave1 = layer-1 consumer
#define CH 16           // timesteps per chunk (one barrier per chunk)
#define NCH (TT / CH)   // 128 chunks -> 128 barriers total
#define NSLOT (2 * CH)  // 32-slot double-buffered h ring

typedef float v2f __attribute__((ext_vector_type(2)));
typedef float v4f __attribute__((ext_vector_type(4)));

// Fast activations on v_exp_f32 / v_rcp_f32 (~1e-7 abs err; threshold 3.45e-6;
// validated at absmax 9.5e-7 in rounds 0-1).
__device__ __forceinline__ float frcp(float x) { return __builtin_amdgcn_rcpf(x); }
__device__ __forceinline__ float fsigmoid(float x) { return frcp(1.0f + __expf(-x)); }
__device__ __forceinline__ float ftanh(float x) { return 1.0f - 2.0f * frcp(1.0f + __expf(2.0f * x)); }

// Packed dual-FMA: a.{x,y} += h.{x,y} * w.{x,y}  (one VOP3P instruction).
__device__ __forceinline__ void pkfma(v2f& a, v2f h, v2f w) {
    asm("v_pk_fma_f32 %0, %1, %2, %0" : "+v"(a) : "v"(h), "v"(w));
}

// ROUND-1 POST-MORTEM: v2f wij[64]/wfo[64] ARRAYS went to scratch (VGPR=148,
// one dispatch fetched 24 GB). Fix: 64 NAMED v4f registers -- named scalars
// always SROA; using them as asm operands every step forces VGPR residency.
// WR{k} = (Wi[k][u], Wj[k][u], Wf[k][u], Wo[k][u]) for h-input k.

// One block per batch element (256 blocks = 1/CU), 2 waves.
// Wave 0 (producer, layer 0): lane u owns unit u = all four gate columns of
//   W0 (256 weights/lane in WR0..WR63). z never leaves registers; no per-step
//   barrier. h broadcast: one ds_write_b64 of the (h,h) splat into the ring,
//   then 32 uniform-address ds_read_b128 (HW broadcast, conflict-free)
//   feeding 128 v_pk_fma_f32 in 8 chains.
// Wave 1 (consumer, layer 1 + dense): processes h in CH=16-step chunks from
//   the 32-slot ring, one __syncthreads per chunk (double-buffered: producer
//   writes chunk k+1 while consumer reads chunk k). Both waves execute
//   exactly 1 + NCH barriers.
__global__ __launch_bounds__(NTHR, 1) void lstm_ts_kernel(
    const float* __restrict__ x, const float* __restrict__ W0,
    const float* __restrict__ b0, const float* __restrict__ W1,
    const float* __restrict__ b1, const float* __restrict__ Wd,
    const float* __restrict__ bd, float* __restrict__ out)
{
    __shared__ __align__(16) float xbuf[TT];
    __shared__ __align__(16) float ring[NSLOT][2 * UU];  // (h,h) splat pairs
    __shared__ float red[2];

    const int tid = threadIdx.x;
    const int wid = tid >> 6;
    const int u = tid & 63;
    const int b = blockIdx.x;
    const float* xrow = x + b * TT;
    float* outrow = out + b * TT;

    // ---- prologue: stage x, sum of squares over T (both waves) ----
    float ss = 0.f;
    for (int i = tid; i < TT; i += NTHR) {
        float v = xrow[i];
        xbuf[i] = v;
        ss += v * v;
    }
    #pragma unroll
    for (int m = 1; m < 64; m <<= 1) ss += __shfl_xor(ss, m, 64);
    if (u == 0) red[wid] = ss;
    __syncthreads();  // B0

    if (wid == 0) {
        // ================= PRODUCER: layer-0 LSTM, one wave =================
        const float sq = red[0] + red[1];
        const float scale = 1.0f / sqrtf(fmaxf(sq, 1e-12f));  // precise, once

        // 64 named v4f = 256 weight VGPRs, guaranteed SROA + asm-pinned.
        #define DECLW(k) v4f WR##k; { const float* r_ = W0 + (1 + k) * 256; \
            WR##k.x = r_[u]; WR##k.y = r_[64 + u]; \
            WR##k.z = r_[128 + u]; WR##k.w = r_[192 + u]; } \
            asm volatile("" : "+v"(WR##k));
        DECLW(0)  DECLW(1)  DECLW(2)  DECLW(3)  DECLW(4)  DECLW(5)  DECLW(6)  DECLW(7)
        DECLW(8)  DECLW(9)  DECLW(10) DECLW(11) DECLW(12) DECLW(13) DECLW(14) DECLW(15)
        DECLW(16) DECLW(17) DECLW(18) DECLW(19) DECLW(20) DECLW(21) DECLW(22) DECLW(23)
        DECLW(24) DECLW(25) DECLW(26) DECLW(27) DECLW(28) DECLW(29) DECLW(30) DECLW(31)
        DECLW(32) DECLW(33) DECLW(34) DECLW(35) DECLW(36) DECLW(37) DECLW(38) DECLW(39)
        DECLW(40) DECLW(41) DECLW(42) DECLW(43) DECLW(44) DECLW(45) DECLW(46) DECLW(47)
        DECLW(48) DECLW(49) DECLW(50) DECLW(51) DECLW(52) DECLW(53) DECLW(54) DECLW(55)
        DECLW(56) DECLW(57) DECLW(58) DECLW(59) DECLW(60) DECLW(61) DECLW(62) DECLW(63)
        #undef DECLW

        const float wxi = W0[u] * scale,       wxj = W0[64 + u] * scale;
        const float wxf = W0[128 + u] * scale, wxo = W0[192 + u] * scale;
        const float bci = b0[u],       bcj = b0[64 + u];
        const float bcf = b0[128 + u], bco = b0[192 + u];

        // h_{-1} = 0 lives in slot NSLOT-1 (step t reads slot (t-1)&31).
        ring[NSLOT - 1][2 * u]     = 0.f;
        ring[NSLOT - 1][2 * u + 1] = 0.f;

        float c0 = 0.f;

        for (int t = 0; t < TT; ++t) {
            const float xr = xbuf[t];  // uniform broadcast read

            // 8 named accumulator chains; x-term folded into chain 0
            v2f ai0, ai1 = 0.f, ai2 = 0.f, ai3 = 0.f;
            v2f af0, af1 = 0.f, af2 = 0.f, af3 = 0.f;
            ai0.x = fmaf(xr, wxi, bci); ai0.y = fmaf(xr, wxj, bcj);
            af0.x = fmaf(xr, wxf, bcf); af0.y = fmaf(xr, wxo, bco);

            const float* hs = ring[(t + NSLOT - 1) & (NSLOT - 1)];

            // k2-th call consumes h_{2k2}, h_{2k2+1}: one uniform b128 read
            // (two splat pairs) + 4 v_pk_fma_f32.
            #define MACPAIR(k2, Wa, Wb, AI, AF) { \
                v4f hv_ = *(const v4f*)(hs + 4 * (k2)); \
                v2f hlo_ = __builtin_shufflevector(hv_, hv_, 0, 1); \
                v2f hhi_ = __builtin_shufflevector(hv_, hv_, 2, 3); \
                pkfma(AI, hlo_, __builtin_shufflevector(Wa, Wa, 0, 1)); \
                pkfma(AF, hlo_, __builtin_shufflevector(Wa, Wa, 2, 3)); \
                pkfma(AI, hhi_, __builtin_shufflevector(Wb, Wb, 0, 1)); \
                pkfma(AF, hhi_, __builtin_shufflevector(Wb, Wb, 2, 3)); \
            }
            MACPAIR(0,  WR0,  WR1,  ai0, af0) MACPAIR(1,  WR2,  WR3,  ai1, af1)
            MACPAIR(2,  WR4,  WR5,  ai2, af2) MACPAIR(3,  WR6,  WR7,  ai3, af3)
            MACPAIR(4,  WR8,  WR9,  ai0, af0) MACPAIR(5,  WR10, WR11, ai1, af1)
            MACPAIR(6,  WR12, WR13, ai2, af2) MACPAIR(7,  WR14, WR15, ai3, af3)
            MACPAIR(8,  WR16, WR17, ai0, af0) MACPAIR(9,  WR18, WR19, ai1, af1)
            MACPAIR(10, WR20, WR21, ai2, af2) MACPAIR(11, WR22, WR23, ai3, af3)
            MACPAIR(12, WR24, WR25, ai0, af0) MACPAIR(13, WR26, WR27, ai1, af1)
            MACPAIR(14, WR28, WR29, ai2, af2) MACPAIR(15, WR30, WR31, ai3, af3)
            MACPAIR(16, WR32, WR33, ai0, af0) MACPAIR(17, WR34, WR35, ai1, af1)
            MACPAIR(18, WR36, WR37, ai2, af2) MACPAIR(19, WR38, WR39, ai3, af3)
            MACPAIR(20, WR40, WR41, ai0, af0) MACPAIR(21, WR42, WR43, ai1, af1)
            MACPAIR(22, WR44, WR45, ai2, af2) MACPAIR(23, WR46, WR47, ai3, af3)
            MACPAIR(24, WR48, WR49, ai0, af0) MACPAIR(25, WR50, WR51, ai1, af1)
            MACPAIR(26, WR52, WR53, ai2, af2) MACPAIR(27, WR54, WR55, ai3, af3)
            MACPAIR(28, WR56, WR57, ai0, af0) MACPAIR(29, WR58, WR59, ai1, af1)
            MACPAIR(30, WR60, WR61, ai2, af2) MACPAIR(31, WR62, WR63, ai3, af3)
            #undef MACPAIR

            v2f zij = (ai0 + ai1) + (ai2 + ai3);
            v2f zfo = (af0 + af1) + (af2 + af3);

            // ---- unit update, z never left registers ----
            c0 = fsigmoid(zfo.x + 1.0f) * c0 + fsigmoid(zij.x) * ftanh(zij.y);
            const float h = fsigmoid(zfo.y) * ftanh(c0);

            // publish (h,h) splat: feeds next step's broadcast AND consumer
            v2f hh; hh.x = h; hh.y = h;
            *(v2f*)(&ring[t & (NSLOT - 1)][2 * u]) = hh;

            if ((t & (CH - 1)) == (CH - 1)) __syncthreads();  // 1 per chunk
        }
    } else {
        // ================= CONSUMER: layer 1 + dense + store =================
        const float w1v0 = W1[u * 4 + 0], w1v1 = W1[u * 4 + 1];
        const float w1v2 = W1[u * 4 + 2], w1v3 = W1[u * 4 + 3];
        const float w1h0 = W1[256], w1h1 = W1[257], w1h2 = W1[258], w1h3 = W1[259];
        const float b10 = b1[0], b11 = b1[1], b12 = b1[2], b13 = b1[3];
        const float wd = Wd[0], bdv = bd[0];

        float c1 = 0.f, h1 = 0.f, oval = 0.f;

        for (int k2 = 0; k2 < NCH; ++k2) {
            __syncthreads();  // chunk k2 is now fully in the ring
            const int sbase = k2 * CH;
            for (int si = 0; si < CH; ++si) {
                const int s = sbase + si;
                const float hu = ring[s & (NSLOT - 1)][2 * u];  // 8B stride: 2-way, free
                float p0 = hu * w1v0, p1 = hu * w1v1, p2 = hu * w1v2, p3 = hu * w1v3;
                #pragma unroll
                for (int m = 1; m < 64; m <<= 1) {
                    p0 += __shfl_xor(p0, m, 64);
                    p1 += __shfl_xor(p1, m, 64);
                    p2 += __shfl_xor(p2, m, 64);
                    p3 += __shfl_xor(p3, m, 64);
                }
                const float z1i = p0 + fmaf(h1, w1h0, b10);
                const float z1j = p1 + fmaf(h1, w1h1, b11);
                const float z1f = p2 + fmaf(h1, w1h2, b12);
                const float z1o = p3 + fmaf(h1, w1h3, b13);
                c1 = fsigmoid(z1f + 1.0f) * c1 + fsigmoid(z1i) * ftanh(z1j);
                h1 = fsigmoid(z1o) * ftanh(c1);
                const float ov = fmaf(h1, wd, bdv);
                if ((s & 63) == u) oval = ov;
                if ((s & 63) == 63) outrow[(s & ~63) + u] = oval;
            }
        }
    }
}

extern "C" void kernel_launch(void* const* d_in, const int* in_sizes, int n_in,
                              void* d_out, int out_size, void* d_ws, size_t ws_size,
                              hipStream_t stream) {
    const float* x  = (const float*)d_in[0];
    const float* W0 = (const float*)d_in[1];
    const float* b0 = (const float*)d_in[2];
    const float* W1 = (const float*)d_in[3];
    const float* b1 = (const float*)d_in[4];
    const float* Wd = (const float*)d_in[5];
    const float* bd = (const float*)d_in[6];
    float* out = (float*)d_out;
    lstm_ts_kernel<<<BB, NTHR, 0, stream>>>(x, W0, b0, W1, b1, Wd, bd, out);
}

// Round 3
// 1182.524 us; speedup vs baseline: 2.4068x; 2.4068x over previous
//
#include <hip/hip_runtime.h>
#include <math.h>

#define TT 2048
#define UU 64
#define BB 256
#define NTHR 192   // 3 waves: wave0 = gates(i,j), wave1 = gates(f,o), wave2 = consumer
#define LDSPAD 12544  // pads total LDS to ~60 KB -> compiler occupancy target 1-2 waves/EU

typedef float v2f __attribute__((ext_vector_type(2)));
typedef float v4f __attribute__((ext_vector_type(4)));

// Fast activations on v_exp_f32 / v_rcp_f32 (~1e-7 abs err; threshold 3.45e-6;
// validated at absmax 9.5e-7 in rounds 0-2).
__device__ __forceinline__ float frcp(float x) { return __builtin_amdgcn_rcpf(x); }
__device__ __forceinline__ float fsigmoid(float x) { return frcp(1.0f + __expf(-x)); }
__device__ __forceinline__ float ftanh(float x) { return 1.0f - 2.0f * frcp(1.0f + __expf(2.0f * x)); }

// Packed dual-FMA: a.{x,y} += h.{x,y} * w.{x,y}  (one VOP3P instruction).
__device__ __forceinline__ void pkfma(v2f& a, v2f h, v2f w) {
    asm("v_pk_fma_f32 %0, %1, %2, %0" : "+v"(a) : "v"(h), "v"(w));
}

// ROUNDS 0-2 POST-MORTEM: the RA's VGPR budget = 512 / (LDS-derived waves/EU
// target). 11KB LDS -> budget 64 (r0, VGPR=40); 25KB -> budget ~170 (r1/r2,
// VGPR=148) -> 256-weight plan spilled to scratch (1.3GB FETCH, VALUBusy 9%).
// Fix: (a) LDS padded to ~60KB -> target 1-2 waves/EU -> budget 256-512;
//      (b) weights split across TWO producer waves: 64 v2f = 128 VGPRs each,
//          total producer pressure ~165 -> fits even a 256 budget.
//
// Wave 0: lane u owns (i,j) columns {u, 64+u} of W0.  Wave 1: (f,o) columns
// {128+u, 192+u}.  Per step: each wave matvecs its 2 gates (32 uniform
// ds_read_b128 h-broadcasts from its PRIVATE splat ring + 64 v_pk_fma_f32),
// writes its (z,z) pair to zb, ONE barrier, both waves read both pairs and
// redundantly compute (c0,h) -- bit-identical in both waves -- then each
// writes its own ring slot (no cross-wave ring race; consumer reads wave0's
// ring one step lagged, round-0's proven protocol).
// Wave 2 (consumer): after barrier t processes step t-1: 4-value 64-lane
// shuffle reduce + layer-1 LSTM + dense, banks output, coalesced flush every
// 64 steps. Its ~300cy overlaps the producers' ~400cy matvec phase.
// All 3 waves execute exactly 1 + TT + 1 barriers.
__global__ __launch_bounds__(NTHR, 1) void lstm_ts_kernel(
    const float* __restrict__ x, const float* __restrict__ W0,
    const float* __restrict__ b0, const float* __restrict__ W1,
    const float* __restrict__ b1, const float* __restrict__ Wd,
    const float* __restrict__ bd, float* __restrict__ out)
{
    __shared__ __align__(16) float xbuf[TT];
    __shared__ __align__(16) float ringS0[2][2 * UU];  // wave0 (h,h) splats
    __shared__ __align__(16) float ringS1[2][2 * UU];  // wave1 private copy
    __shared__ __align__(16) v2f zb0[UU];              // (z_i, z_j) per unit
    __shared__ __align__(16) v2f zb1[UU];              // (z_f, z_o) per unit
    __shared__ float red[3];
    __shared__ float ldspad[LDSPAD];                   // occupancy-shaping pad

    const int tid = threadIdx.x;
    const int wid = tid >> 6;
    const int u = tid & 63;
    const int b = blockIdx.x;
    const float* xrow = x + b * TT;
    float* outrow = out + b * TT;

    // keep the pad allocated (never executes: blockIdx.x is never -1)
    if (b == -1) outrow[0] = ldspad[tid];

    // ---- prologue: stage x, sum of squares over T (all 3 waves) ----
    float ss = 0.f;
    for (int i = tid; i < TT; i += NTHR) {
        float v = xrow[i];
        xbuf[i] = v;
        ss += v * v;
    }
    #pragma unroll
    for (int m = 1; m < 64; m <<= 1) ss += __shfl_xor(ss, m, 64);
    if (u == 0) red[wid] = ss;
    if (wid < 2) {  // h_{-1} = 0: step 0 reads slot 1
        float* r1 = (wid == 0 ? ringS0 : ringS1)[1];
        r1[2 * u] = 0.f; r1[2 * u + 1] = 0.f;
    }
    __syncthreads();  // B0

    if (wid < 2) {
        // ============ PRODUCER wave 'wid': gate pair (i,j) or (f,o) ============
        const int go = wid * 128;  // column offset: 0 -> (i,j), 128 -> (f,o)
        const float sq = (red[0] + red[1]) + red[2];
        const float scale = 1.0f / sqrtf(fmaxf(sq, 1e-12f));  // precise, once

        // 64 named v2f = 128 weight VGPRs; named scalars SROA, pins block remat.
        #define DECLW(k) v2f WP##k; { const float* r_ = W0 + (1 + (k)) * 256 + go; \
            WP##k.x = r_[u]; WP##k.y = r_[64 + u]; } \
            asm volatile("" : "+v"(WP##k));
        DECLW(0)  DECLW(1)  DECLW(2)  DECLW(3)  DECLW(4)  DECLW(5)  DECLW(6)  DECLW(7)
        DECLW(8)  DECLW(9)  DECLW(10) DECLW(11) DECLW(12) DECLW(13) DECLW(14) DECLW(15)
        DECLW(16) DECLW(17) DECLW(18) DECLW(19) DECLW(20) DECLW(21) DECLW(22) DECLW(23)
        DECLW(24) DECLW(25) DECLW(26) DECLW(27) DECLW(28) DECLW(29) DECLW(30) DECLW(31)
        DECLW(32) DECLW(33) DECLW(34) DECLW(35) DECLW(36) DECLW(37) DECLW(38) DECLW(39)
        DECLW(40) DECLW(41) DECLW(42) DECLW(43) DECLW(44) DECLW(45) DECLW(46) DECLW(47)
        DECLW(48) DECLW(49) DECLW(50) DECLW(51) DECLW(52) DECLW(53) DECLW(54) DECLW(55)
        DECLW(56) DECLW(57) DECLW(58) DECLW(59) DECLW(60) DECLW(61) DECLW(62) DECLW(63)
        #undef DECLW

        const float wxa = W0[go + u] * scale;       // x-weight, gate a (i or f)
        const float wxb = W0[go + 64 + u] * scale;  // gate b (j or o)
        const float bca = b0[go + u], bcb = b0[go + 64 + u];

        float (*myring)[2 * UU] = (wid == 0) ? ringS0 : ringS1;
        v2f* zbme = (wid == 0) ? zb0 : zb1;

        float c0 = 0.f;

        for (int t = 0; t < TT; ++t) {
            const float xr = xbuf[t];  // uniform broadcast read
            const float* hs = myring[(t + 1) & 1];  // h_{t-1} splats (own copy)

            // 4 chains x 16 deep (same depth as validated r1/r2 numerics);
            // x-term folded into chain 0.
            v2f a0, a1 = 0.f, a2 = 0.f, a3 = 0.f;
            a0.x = fmaf(xr, wxa, bca); a0.y = fmaf(xr, wxb, bcb);

            // one uniform b128 read = (h2k,h2k,h2k+1,h2k+1) -> 2 pk_fma
            #define MAC2(k2, Wa, Wb, Ae, Ao) { \
                v4f hv_ = *(const v4f*)(hs + 4 * (k2)); \
                v2f hlo_ = __builtin_shufflevector(hv_, hv_, 0, 1); \
                v2f hhi_ = __builtin_shufflevector(hv_, hv_, 2, 3); \
                pkfma(Ae, hlo_, Wa); pkfma(Ao, hhi_, Wb); \
            }
            MAC2(0,  WP0,  WP1,  a0, a1) MAC2(1,  WP2,  WP3,  a2, a3)
            MAC2(2,  WP4,  WP5,  a0, a1) MAC2(3,  WP6,  WP7,  a2, a3)
            MAC2(4,  WP8,  WP9,  a0, a1) MAC2(5,  WP10, WP11, a2, a3)
            MAC2(6,  WP12, WP13, a0, a1) MAC2(7,  WP14, WP15, a2, a3)
            MAC2(8,  WP16, WP17, a0, a1) MAC2(9,  WP18, WP19, a2, a3)
            MAC2(10, WP20, WP21, a0, a1) MAC2(11, WP22, WP23, a2, a3)
            MAC2(12, WP24, WP25, a0, a1) MAC2(13, WP26, WP27, a2, a3)
            MAC2(14, WP28, WP29, a0, a1) MAC2(15, WP30, WP31, a2, a3)
            MAC2(16, WP32, WP33, a0, a1) MAC2(17, WP34, WP35, a2, a3)
            MAC2(18, WP36, WP37, a0, a1) MAC2(19, WP38, WP39, a2, a3)
            MAC2(20, WP40, WP41, a0, a1) MAC2(21, WP42, WP43, a2, a3)
            MAC2(22, WP44, WP45, a0, a1) MAC2(23, WP46, WP47, a2, a3)
            MAC2(24, WP48, WP49, a0, a1) MAC2(25, WP50, WP51, a2, a3)
            MAC2(26, WP52, WP53, a0, a1) MAC2(27, WP54, WP55, a2, a3)
            MAC2(28, WP56, WP57, a0, a1) MAC2(29, WP58, WP59, a2, a3)
            MAC2(30, WP60, WP61, a0, a1) MAC2(31, WP62, WP63, a2, a3)
            #undef MAC2

            zbme[u] = (a0 + a1) + (a2 + a3);  // (z_a, z_b) -> ds_write_b64
            __syncthreads();  // B(t+1): z pairs exchanged

            // redundant unit update -- bit-identical in both producer waves
            const v2f zij = zb0[u];
            const v2f zfo = zb1[u];
            c0 = fsigmoid(zfo.x + 1.0f) * c0 + fsigmoid(zij.x) * ftanh(zij.y);
            const float h = fsigmoid(zfo.y) * ftanh(c0);

            v2f hh; hh.x = h; hh.y = h;
            *(v2f*)(&myring[t & 1][2 * u]) = hh;  // own splat ring
        }
        __syncthreads();  // B(TT+1)
    } else {
        // ================= CONSUMER: layer 1 + dense + store =================
        const float w1v0 = W1[u * 4 + 0], w1v1 = W1[u * 4 + 1];
        const float w1v2 = W1[u * 4 + 2], w1v3 = W1[u * 4 + 3];
        const float w1h0 = W1[256], w1h1 = W1[257], w1h2 = W1[258], w1h3 = W1[259];
        const float b10 = b1[0], b11 = b1[1], b12 = b1[2], b13 = b1[3];
        const float wd = Wd[0], bdv = bd[0];

        float c1 = 0.f, h1 = 0.f, oval = 0.f;

        // reads wave0's ring one step lagged: slot (s)&1 written before
        // barrier s+1, read after it, overwritten only after barrier s+2.
        #define L1STEP(s) { \
            const float hu = ringS0[(s) & 1][2 * u];  /* 8B stride: 2-way, free */ \
            float p0 = hu * w1v0, p1 = hu * w1v1, p2 = hu * w1v2, p3 = hu * w1v3; \
            _Pragma("unroll") \
            for (int m = 1; m < 64; m <<= 1) { \
                p0 += __shfl_xor(p0, m, 64); \
                p1 += __shfl_xor(p1, m, 64); \
                p2 += __shfl_xor(p2, m, 64); \
                p3 += __shfl_xor(p3, m, 64); \
            } \
            const float z1i = p0 + fmaf(h1, w1h0, b10); \
            const float z1j = p1 + fmaf(h1, w1h1, b11); \
            const float z1f = p2 + fmaf(h1, w1h2, b12); \
            const float z1o = p3 + fmaf(h1, w1h3, b13); \
            c1 = fsigmoid(z1f + 1.0f) * c1 + fsigmoid(z1i) * ftanh(z1j); \
            h1 = fsigmoid(z1o) * ftanh(c1); \
            const float ov = fmaf(h1, wd, bdv); \
            if (((s) & 63) == u) oval = ov; \
            if (((s) & 63) == 63) outrow[((s) & ~63) + u] = oval; \
        }

        for (int t = 0; t < TT; ++t) {
            __syncthreads();  // B(t+1)
            if (t > 0) L1STEP(t - 1)
        }
        __syncthreads();  // B(TT+1) -- makes ring slot (TT-1)&1 visible
        L1STEP(TT - 1)
        #undef L1STEP
    }
}

extern "C" void kernel_launch(void* const* d_in, const int* in_sizes, int n_in,
                              void* d_out, int out_size, void* d_ws, size_t ws_size,
                              hipStream_t stream) {
    const float* x  = (const float*)d_in[0];
    const float* W0 = (const float*)d_in[1];
    const float* b0 = (const float*)d_in[2];
    const float* W1 = (const float*)d_in[3];
    const float* b1 = (const float*)d_in[4];
    const float* Wd = (const float*)d_in[5];
    const float* bd = (const float*)d_in[6];
    float* out = (float*)d_out;
    lstm_ts_kernel<<<BB, NTHR, 0, stream>>>(x, W0, b0, W1, b1, Wd, bd, out);
}

// Round 4
// 1102.561 us; speedup vs baseline: 2.5814x; 1.0725x over previous
//
#include <hip/hip_runtime.h>
#include <math.h>

#define TT 2048
#define UU 64
#define BB 256
#define NTHR 192   // 3 waves: wave0 = gates(i,j), wave1 = gates(f,o), wave2 = consumer

typedef float v2f __attribute__((ext_vector_type(2)));
typedef float v4f __attribute__((ext_vector_type(4)));

// Fast activations on v_exp_f32 / v_rcp_f32 (~1e-7 abs err; threshold 3.45e-6;
// validated at absmax 9.5e-7 in rounds 0-3).
__device__ __forceinline__ float frcp(float x) { return __builtin_amdgcn_rcpf(x); }
__device__ __forceinline__ float fsigmoid(float x) { return frcp(1.0f + __expf(-x)); }
__device__ __forceinline__ float ftanh(float x) { return 1.0f - 2.0f * frcp(1.0f + __expf(2.0f * x)); }

// Packed dual-FMA: a.{x,y} += h.{x,y} * w.{x,y}  (one VOP3P instruction).
__device__ __forceinline__ void pkfma(v2f& a, v2f h, v2f w) {
    asm("v_pk_fma_f32 %0, %1, %2, %0" : "+v"(a) : "v"(h), "v"(w));
}

// ROUNDS 0-3 POST-MORTEM: the backend's register-pressure target comes from
// its occupancy heuristic; __launch_bounds__(N,1) does NOT lower it, and the
// LDS pad (r3) was DCE'd. Result: RA remats the 128 weight loads every step
// (r3: VGPR=84, VALUBusy 23%, 1385 cyc/step of L2-reload latency).
// FIX: amdgpu_waves_per_eu(1,1) pins max waves/EU = 1 -> pressure budget 512
// VGPRs -> MachineLICM hoists the weight loads; weights stay live.
//
// Structure (unchanged from r3, which passed at 1182us):
// Wave 0: lane u owns (i,j) columns {u, 64+u} of W0. Wave 1: (f,o) columns
// {128+u, 192+u}. Per step: each wave matvecs its 2 gates (32 uniform
// ds_read_b128 h-broadcasts from its PRIVATE splat ring + 64 v_pk_fma_f32),
// writes its (z,z) pair to zb, ONE barrier, both waves read both pairs and
// redundantly compute (c0,h) -- bit-identical in both waves -- then each
// writes its own ring slot (consumer reads wave0's ring one step lagged,
// round-0's proven protocol).
// Wave 2 (consumer): after barrier t processes step t-1: 4-value 64-lane
// shuffle reduce + layer-1 LSTM + dense, banks output, coalesced flush every
// 64 steps. Overlaps the producers' matvec phase.
// All 3 waves execute exactly 1 + TT + 1 barriers.
__global__
__attribute__((amdgpu_flat_work_group_size(NTHR, NTHR)))
__attribute__((amdgpu_waves_per_eu(1, 1)))
void lstm_ts_kernel(
    const float* __restrict__ x, const float* __restrict__ W0,
    const float* __restrict__ b0, const float* __restrict__ W1,
    const float* __restrict__ b1, const float* __restrict__ Wd,
    const float* __restrict__ bd, float* __restrict__ out)
{
    __shared__ __align__(16) float xbuf[TT];
    __shared__ __align__(16) float ringS0[2][2 * UU];  // wave0 (h,h) splats
    __shared__ __align__(16) float ringS1[2][2 * UU];  // wave1 private copy
    __shared__ __align__(16) v2f zb0[UU];              // (z_i, z_j) per unit
    __shared__ __align__(16) v2f zb1[UU];              // (z_f, z_o) per unit
    __shared__ float red[3];

    const int tid = threadIdx.x;
    const int wid = tid >> 6;
    const int u = tid & 63;
    const int b = blockIdx.x;
    const float* xrow = x + b * TT;
    float* outrow = out + b * TT;

    // ---- prologue: stage x, sum of squares over T (all 3 waves) ----
    float ss = 0.f;
    for (int i = tid; i < TT; i += NTHR) {
        float v = xrow[i];
        xbuf[i] = v;
        ss += v * v;
    }
    #pragma unroll
    for (int m = 1; m < 64; m <<= 1) ss += __shfl_xor(ss, m, 64);
    if (u == 0) red[wid] = ss;
    if (wid < 2) {  // h_{-1} = 0: step 0 reads slot 1
        float* r1 = (wid == 0 ? ringS0 : ringS1)[1];
        r1[2 * u] = 0.f; r1[2 * u + 1] = 0.f;
    }
    __syncthreads();  // B0

    if (wid < 2) {
        // ============ PRODUCER wave 'wid': gate pair (i,j) or (f,o) ============
        const int go = wid * 128;  // column offset: 0 -> (i,j), 128 -> (f,o)
        const float sq = (red[0] + red[1]) + red[2];
        const float scale = 1.0f / sqrtf(fmaxf(sq, 1e-12f));  // precise, once

        // 64 named v2f = 128 weight VGPRs; named scalars SROA, pins block remat.
        #define DECLW(k) v2f WP##k; { const float* r_ = W0 + (1 + (k)) * 256 + go; \
            WP##k.x = r_[u]; WP##k.y = r_[64 + u]; } \
            asm volatile("" : "+v"(WP##k));
        DECLW(0)  DECLW(1)  DECLW(2)  DECLW(3)  DECLW(4)  DECLW(5)  DECLW(6)  DECLW(7)
        DECLW(8)  DECLW(9)  DECLW(10) DECLW(11) DECLW(12) DECLW(13) DECLW(14) DECLW(15)
        DECLW(16) DECLW(17) DECLW(18) DECLW(19) DECLW(20) DECLW(21) DECLW(22) DECLW(23)
        DECLW(24) DECLW(25) DECLW(26) DECLW(27) DECLW(28) DECLW(29) DECLW(30) DECLW(31)
        DECLW(32) DECLW(33) DECLW(34) DECLW(35) DECLW(36) DECLW(37) DECLW(38) DECLW(39)
        DECLW(40) DECLW(41) DECLW(42) DECLW(43) DECLW(44) DECLW(45) DECLW(46) DECLW(47)
        DECLW(48) DECLW(49) DECLW(50) DECLW(51) DECLW(52) DECLW(53) DECLW(54) DECLW(55)
        DECLW(56) DECLW(57) DECLW(58) DECLW(59) DECLW(60) DECLW(61) DECLW(62) DECLW(63)
        #undef DECLW

        const float wxa = W0[go + u] * scale;       // x-weight, gate a (i or f)
        const float wxb = W0[go + 64 + u] * scale;  // gate b (j or o)
        const float bca = b0[go + u], bcb = b0[go + 64 + u];

        float (*myring)[2 * UU] = (wid == 0) ? ringS0 : ringS1;
        v2f* zbme = (wid == 0) ? zb0 : zb1;

        float c0 = 0.f;

        for (int t = 0; t < TT; ++t) {
            const float xr = xbuf[t];  // uniform broadcast read
            const float* hs = myring[(t + 1) & 1];  // h_{t-1} splats (own copy)

            // 4 chains x 16 deep (same depth as validated r1-r3 numerics);
            // x-term folded into chain 0.
            v2f a0, a1 = 0.f, a2 = 0.f, a3 = 0.f;
            a0.x = fmaf(xr, wxa, bca); a0.y = fmaf(xr, wxb, bcb);

            // one uniform b128 read = (h2k,h2k,h2k+1,h2k+1) -> 2 pk_fma
            #define MAC2(k2, Wa, Wb, Ae, Ao) { \
                v4f hv_ = *(const v4f*)(hs + 4 * (k2)); \
                v2f hlo_ = __builtin_shufflevector(hv_, hv_, 0, 1); \
                v2f hhi_ = __builtin_shufflevector(hv_, hv_, 2, 3); \
                pkfma(Ae, hlo_, Wa); pkfma(Ao, hhi_, Wb); \
            }
            MAC2(0,  WP0,  WP1,  a0, a1) MAC2(1,  WP2,  WP3,  a2, a3)
            MAC2(2,  WP4,  WP5,  a0, a1) MAC2(3,  WP6,  WP7,  a2, a3)
            MAC2(4,  WP8,  WP9,  a0, a1) MAC2(5,  WP10, WP11, a2, a3)
            MAC2(6,  WP12, WP13, a0, a1) MAC2(7,  WP14, WP15, a2, a3)
            MAC2(8,  WP16, WP17, a0, a1) MAC2(9,  WP18, WP19, a2, a3)
            MAC2(10, WP20, WP21, a0, a1) MAC2(11, WP22, WP23, a2, a3)
            MAC2(12, WP24, WP25, a0, a1) MAC2(13, WP26, WP27, a2, a3)
            MAC2(14, WP28, WP29, a0, a1) MAC2(15, WP30, WP31, a2, a3)
            MAC2(16, WP32, WP33, a0, a1) MAC2(17, WP34, WP35, a2, a3)
            MAC2(18, WP36, WP37, a0, a1) MAC2(19, WP38, WP39, a2, a3)
            MAC2(20, WP40, WP41, a0, a1) MAC2(21, WP42, WP43, a2, a3)
            MAC2(22, WP44, WP45, a0, a1) MAC2(23, WP46, WP47, a2, a3)
            MAC2(24, WP48, WP49, a0, a1) MAC2(25, WP50, WP51, a2, a3)
            MAC2(26, WP52, WP53, a0, a1) MAC2(27, WP54, WP55, a2, a3)
            MAC2(28, WP56, WP57, a0, a1) MAC2(29, WP58, WP59, a2, a3)
            MAC2(30, WP60, WP61, a0, a1) MAC2(31, WP62, WP63, a2, a3)
            #undef MAC2

            zbme[u] = (a0 + a1) + (a2 + a3);  // (z_a, z_b) -> ds_write_b64
            __syncthreads();  // B(t+1): z pairs exchanged

            // redundant unit update -- bit-identical in both producer waves
            const v2f zij = zb0[u];
            const v2f zfo = zb1[u];
            c0 = fsigmoid(zfo.x + 1.0f) * c0 + fsigmoid(zij.x) * ftanh(zij.y);
            const float h = fsigmoid(zfo.y) * ftanh(c0);

            v2f hh; hh.x = h; hh.y = h;
            *(v2f*)(&myring[t & 1][2 * u]) = hh;  // own splat ring
        }
        __syncthreads();  // B(TT+1)
    } else {
        // ================= CONSUMER: layer 1 + dense + store =================
        const float w1v0 = W1[u * 4 + 0], w1v1 = W1[u * 4 + 1];
        const float w1v2 = W1[u * 4 + 2], w1v3 = W1[u * 4 + 3];
        const float w1h0 = W1[256], w1h1 = W1[257], w1h2 = W1[258], w1h3 = W1[259];
        const float b10 = b1[0], b11 = b1[1], b12 = b1[2], b13 = b1[3];
        const float wd = Wd[0], bdv = bd[0];

        float c1 = 0.f, h1 = 0.f, oval = 0.f;

        // reads wave0's ring one step lagged: slot (s)&1 written before
        // barrier s+1, read after it, overwritten only after barrier s+2.
        #define L1STEP(s) { \
            const float hu = ringS0[(s) & 1][2 * u];  /* 8B stride: 2-way, free */ \
            float p0 = hu * w1v0, p1 = hu * w1v1, p2 = hu * w1v2, p3 = hu * w1v3; \
            _Pragma("unroll") \
            for (int m = 1; m < 64; m <<= 1) { \
                p0 += __shfl_xor(p0, m, 64); \
                p1 += __shfl_xor(p1, m, 64); \
                p2 += __shfl_xor(p2, m, 64); \
                p3 += __shfl_xor(p3, m, 64); \
            } \
            const float z1i = p0 + fmaf(h1, w1h0, b10); \
            const float z1j = p1 + fmaf(h1, w1h1, b11); \
            const float z1f = p2 + fmaf(h1, w1h2, b12); \
            const float z1o = p3 + fmaf(h1, w1h3, b13); \
            c1 = fsigmoid(z1f + 1.0f) * c1 + fsigmoid(z1i) * ftanh(z1j); \
            h1 = fsigmoid(z1o) * ftanh(c1); \
            const float ov = fmaf(h1, wd, bdv); \
            if (((s) & 63) == u) oval = ov; \
            if (((s) & 63) == 63) outrow[((s) & ~63) + u] = oval; \
        }

        for (int t = 0; t < TT; ++t) {
            __syncthreads();  // B(t+1)
            if (t > 0) L1STEP(t - 1)
        }
        __syncthreads();  // B(TT+1) -- makes ring slot (TT-1)&1 visible
        L1STEP(TT - 1)
        #undef L1STEP
    }
}

extern "C" void kernel_launch(void* const* d_in, const int* in_sizes, int n_in,
                              void* d_out, int out_size, void* d_ws, size_t ws_size,
                              hipStream_t stream) {
    const float* x  = (const float*)d_in[0];
    const float* W0 = (const float*)d_in[1];
    const float* b0 = (const float*)d_in[2];
    const float* W1 = (const float*)d_in[3];
    const float* b1 = (const float*)d_in[4];
    const float* Wd = (const float*)d_in[5];
    const float* bd = (const float*)d_in[6];
    float* out = (float*)d_out;
    lstm_ts_kernel<<<BB, NTHR, 0, stream>>>(x, W0, b0, W1, b1, Wd, bd, out);
}